// Round 1
// baseline (103.924 us; speedup 1.0000x reference)
//
#include <hip/hip_runtime.h>

// Problem constants (reference: B, LQ, LK, H = 4, 512, 512, 128)
#define B_   4
#define LQ_  512
#define LK_  512
#define H_   128

#define RPB  4      // rows per block in projection kernel
#define QPT  4      // q-values per thread in score kernel
#define KTH  256    // threads per block (one k per thread) in score kernel

// ---------------------------------------------------------------------------
// Kernel 1: Q2[b,q,h] = C * (queries[b,q,:] . U[:,h])
//           K2[b,k,h] = C * (keys[b,k,:]    . T[:,h] + bias[h])
// where C = 2*log2(e), so that exp(2*s) == exp2(Q2 + K2).
// blockIdx.y selects side (0=q, 1=k). One block = RPB rows, 128 threads = h.
// X-row reads are wave-uniform -> scalar loads; M reads coalesced over h.
// ---------------------------------------------------------------------------
__global__ __launch_bounds__(128) void proj_kernel(
    const float* __restrict__ queries, const float* __restrict__ keys,
    const float* __restrict__ U, const float* __restrict__ T,
    const float* __restrict__ bvec,
    float* __restrict__ Q2, float* __restrict__ K2)
{
    const int side = blockIdx.y;  // 0 = q-side, 1 = k-side
    const float* __restrict__ X = side ? keys : queries;
    const float* __restrict__ M = side ? T : U;
    float* __restrict__ Y       = side ? K2 : Q2;

    const int t  = threadIdx.x;          // h index, 0..127
    const int r0 = blockIdx.x * RPB;     // first row of this block

    float acc[RPB];
#pragma unroll
    for (int i = 0; i < RPB; ++i) acc[i] = 0.f;

#pragma unroll 8
    for (int d = 0; d < H_; ++d) {
        float m = M[d * H_ + t];                      // coalesced across lanes
#pragma unroll
        for (int i = 0; i < RPB; ++i)                 // uniform addr -> s_load
            acc[i] = fmaf(X[(size_t)(r0 + i) * H_ + d], m, acc[i]);
    }

    const float C = 2.8853900817779268f;  // 2 * log2(e)
    const float bb = side ? bvec[t] : 0.f;
#pragma unroll
    for (int i = 0; i < RPB; ++i)
        Y[(size_t)(r0 + i) * H_ + t] = C * (acc[i] + bb);
}

// ---------------------------------------------------------------------------
// Kernel 2: out[b,q,k] = (Sum_h w[h] + w_bias) - 2 * Sum_h w[h]/(exp2(Q2+K2)+1)
// Thread owns one k (lanes contiguous in k -> coalesced stores) and QPT q.
// K2 chunk (8 h) lives in VGPRs, reused across QPT q-values. Q2 and w reads
// are wave-uniform -> scalar loads. Inner body: add, exp2, add, rcp, fmac.
// ---------------------------------------------------------------------------
__global__ __launch_bounds__(KTH) void score_kernel(
    const float* __restrict__ Q2, const float* __restrict__ K2,
    const float* __restrict__ w, const float* __restrict__ wb,
    float* __restrict__ out)
{
    const int b  = blockIdx.z;
    const int q0 = blockIdx.y * QPT;
    const int k  = blockIdx.x * KTH + threadIdx.x;

    const float* __restrict__ q2r = Q2 + ((size_t)b * LQ_ + q0) * H_;
    const float* __restrict__ k2r = K2 + ((size_t)b * LK_ + k) * H_;

    float acc[QPT];
#pragma unroll
    for (int i = 0; i < QPT; ++i) acc[i] = 0.f;

#pragma unroll 4
    for (int c = 0; c < H_; c += 8) {
        float4 a0 = *(const float4*)(k2r + c);
        float4 a1 = *(const float4*)(k2r + c + 4);
        float kk[8] = {a0.x, a0.y, a0.z, a0.w, a1.x, a1.y, a1.z, a1.w};
#pragma unroll
        for (int q = 0; q < QPT; ++q) {
#pragma unroll
            for (int j = 0; j < 8; ++j) {
                float tqk = q2r[q * H_ + c + j] + kk[j];        // s_load + v_add
                float e   = __builtin_amdgcn_exp2f(tqk);        // v_exp_f32
                float r   = __builtin_amdgcn_rcpf(e + 1.0f);    // v_add + v_rcp
                acc[q] = fmaf(w[c + j], r, acc[q]);             // v_fmac (w in sgpr)
            }
        }
    }

    // base = w_bias + Sum_h w[h]   (uniform, scalar loads; tanh = 1 - 2r)
    float base = wb[0];
#pragma unroll 16
    for (int i = 0; i < H_; ++i) base += w[i];

#pragma unroll
    for (int q = 0; q < QPT; ++q)
        out[((size_t)b * LQ_ + q0 + q) * LK_ + k] = fmaf(-2.f, acc[q], base);
}

// ---------------------------------------------------------------------------
extern "C" void kernel_launch(void* const* d_in, const int* in_sizes, int n_in,
                              void* d_out, int out_size, void* d_ws, size_t ws_size,
                              hipStream_t stream)
{
    const float* queries = (const float*)d_in[0];
    const float* keys    = (const float*)d_in[1];
    const float* U       = (const float*)d_in[2];
    const float* T       = (const float*)d_in[3];
    const float* bvec    = (const float*)d_in[4];
    const float* w       = (const float*)d_in[5];
    const float* wb      = (const float*)d_in[6];
    float* out = (float*)d_out;

    float* Q2 = (float*)d_ws;                         // B*LQ*H fp32 = 1 MB
    float* K2 = Q2 + (size_t)B_ * LQ_ * H_;           // B*LK*H fp32 = 1 MB

    proj_kernel<<<dim3((B_ * LQ_) / RPB, 2), 128, 0, stream>>>(
        queries, keys, U, T, bvec, Q2, K2);

    score_kernel<<<dim3(LK_ / KTH, LQ_ / QPT, B_), KTH, 0, stream>>>(
        Q2, K2, w, wb, out);
}

// Round 2
// 92.774 us; speedup vs baseline: 1.1202x; 1.1202x over previous
//
#include <hip/hip_runtime.h>

// Problem constants (reference: B, LQ, LK, H = 4, 512, 512, 128)
#define B_   4
#define LQ_  512
#define LK_  512
#define H_   128

#define RPB  4      // rows per block in projection kernel
#define QPT  4      // q-values per thread in score kernel
#define KTH  256    // threads per block (one k per thread) in score kernel

// ws layout: Eq [B*LQ*H] | Ek [B*LK*H] | base [1]
//
// Math: tanh(s) = 1 - 2/(e^{2s}+1);  e^{2s} = Eq*Ek with
//   Eq = exp2(C*qU), Ek = exp2(C*(kT+b)), C = 2*log2(e).
// out[b,q,k] = (sum_h w_h + w_bias) - 2 * sum_h w_h / (Eq*Ek + 1)

// ---------------------------------------------------------------------------
// Kernel 1: projections + exp2 epilogue. blockIdx.y: 0=q-side, 1=k-side.
// One block = RPB rows, 128 threads over h. M reads coalesced; X reads
// wave-uniform -> scalar loads. Also computes base = w_bias + sum(w) once.
// ---------------------------------------------------------------------------
__global__ __launch_bounds__(128) void proj_kernel(
    const float* __restrict__ queries, const float* __restrict__ keys,
    const float* __restrict__ U, const float* __restrict__ T,
    const float* __restrict__ bvec, const float* __restrict__ w,
    const float* __restrict__ wb,
    float* __restrict__ Eq, float* __restrict__ Ek, float* __restrict__ base)
{
    const int side = blockIdx.y;  // 0 = q-side, 1 = k-side
    const float* __restrict__ X = side ? keys : queries;
    const float* __restrict__ M = side ? T : U;
    float* __restrict__ Y       = side ? Ek : Eq;

    const int t  = threadIdx.x;          // h index, 0..127
    const int r0 = blockIdx.x * RPB;     // first row of this block

    // one thread computes base = w_bias + sum(w); overlapped with the GEMM
    if (side == 1 && blockIdx.x == 0 && t == 0) {
        float s = wb[0];
        for (int h = 0; h < H_; ++h) s += w[h];
        base[0] = s;
    }

    float acc[RPB];
#pragma unroll
    for (int i = 0; i < RPB; ++i) acc[i] = 0.f;

#pragma unroll 8
    for (int d = 0; d < H_; ++d) {
        float m = M[d * H_ + t];                      // coalesced across lanes
#pragma unroll
        for (int i = 0; i < RPB; ++i)                 // uniform addr -> s_load
            acc[i] = fmaf(X[(size_t)(r0 + i) * H_ + d], m, acc[i]);
    }

    const float C = 2.8853900817779268f;  // 2 * log2(e)
    const float bb = side ? bvec[t] : 0.f;
#pragma unroll
    for (int i = 0; i < RPB; ++i)
        Y[(size_t)(r0 + i) * H_ + t] =
            __builtin_amdgcn_exp2f(C * (acc[i] + bb));
}

// ---------------------------------------------------------------------------
// Kernel 2: rational-pair reduction, 1 v_rcp_f32 per 4 h:
//   sum_i w_i/x_i over 4 terms = (n01*d23 + n23*d01) / (d01*d23),
//   x_i = fma(Eq_i, Ek_i, 1), d01=x0*x1, n01 = w0*x1 + w1*x0, etc.
// 14 plain VALU + 1 trans per 4 elements ~= 9 SIMD-cyc/element.
// Thread owns one k (coalesced stores) and QPT q-rows (Eq/w via s_load).
// ---------------------------------------------------------------------------
__global__ __launch_bounds__(KTH) void score_kernel(
    const float* __restrict__ Eq, const float* __restrict__ Ek,
    const float* __restrict__ w, const float* __restrict__ base_p,
    float* __restrict__ out)
{
    const int b  = blockIdx.z;
    const int q0 = blockIdx.y * QPT;
    const int k  = blockIdx.x * KTH + threadIdx.x;

    const float* __restrict__ eqr = Eq + ((size_t)b * LQ_ + q0) * H_;
    const float* __restrict__ ekr = Ek + ((size_t)b * LK_ + k) * H_;

    float acc[QPT];
#pragma unroll
    for (int i = 0; i < QPT; ++i) acc[i] = 0.f;

#pragma unroll 4
    for (int c = 0; c < H_; c += 4) {
        float4 ek4 = *(const float4*)(ekr + c);         // 16B vector load
        float w0 = w[c], w1 = w[c + 1], w2 = w[c + 2], w3 = w[c + 3];
#pragma unroll
        for (int q = 0; q < QPT; ++q) {
            const float* eq = eqr + q * H_ + c;          // uniform -> s_load
            float x0 = fmaf(eq[0], ek4.x, 1.f);
            float x1 = fmaf(eq[1], ek4.y, 1.f);
            float x2 = fmaf(eq[2], ek4.z, 1.f);
            float x3 = fmaf(eq[3], ek4.w, 1.f);
            float d01 = x0 * x1;
            float d23 = x2 * x3;
            float n01 = fmaf(w1, x0, w0 * x1);
            float n23 = fmaf(w3, x2, w2 * x3);
            float num = fmaf(n23, d01, n01 * d23);
            float den = d01 * d23;
            acc[q] = fmaf(num, __builtin_amdgcn_rcpf(den), acc[q]);
        }
    }

    const float base = base_p[0];                        // uniform -> s_load
#pragma unroll
    for (int q = 0; q < QPT; ++q)
        out[((size_t)b * LQ_ + q0 + q) * LK_ + k] = fmaf(-2.f, acc[q], base);
}

// ---------------------------------------------------------------------------
extern "C" void kernel_launch(void* const* d_in, const int* in_sizes, int n_in,
                              void* d_out, int out_size, void* d_ws, size_t ws_size,
                              hipStream_t stream)
{
    const float* queries = (const float*)d_in[0];
    const float* keys    = (const float*)d_in[1];
    const float* U       = (const float*)d_in[2];
    const float* T       = (const float*)d_in[3];
    const float* bvec    = (const float*)d_in[4];
    const float* w       = (const float*)d_in[5];
    const float* wb      = (const float*)d_in[6];
    float* out = (float*)d_out;

    float* Eq   = (float*)d_ws;                        // B*LQ*H fp32 = 1 MB
    float* Ek   = Eq + (size_t)B_ * LQ_ * H_;          // B*LK*H fp32 = 1 MB
    float* base = Ek + (size_t)B_ * LK_ * H_;          // 1 float

    proj_kernel<<<dim3((B_ * LQ_) / RPB, 2), 128, 0, stream>>>(
        queries, keys, U, T, bvec, w, wb, Eq, Ek, base);

    score_kernel<<<dim3(LK_ / KTH, LQ_ / QPT, B_), KTH, 0, stream>>>(
        Eq, Ek, w, base, out);
}

// Round 3
// 91.316 us; speedup vs baseline: 1.1381x; 1.0160x over previous
//
#include <hip/hip_runtime.h>

// Problem constants (reference: B, LQ, LK, H = 4, 512, 512, 128)
#define B_   4
#define LQ_  512
#define LK_  512
#define H_   128

#define RPB  4      // rows per block in projection kernel
#define QPT  8      // q-values per thread in score kernel
#define KTH  256    // threads per block (one k per thread) in score kernel

// ws layout: Eq [B*LQ*H] | EkT [B*LK*H] | base [1]
//
// Math: tanh(s) = 1 - 2/(e^{2s}+1);  e^{2s} = Eq*Ek with
//   Eq = exp2(C*qU), Ek = exp2(C*(kT+b)), C = 2*log2(e).
// out[b,q,k] = (sum_h w_h + w_bias) - 2 * sum_h w_h / (Eq*Ek + 1)
//
// EkT is stored k-interleaved for coalescing in the score kernel:
//   EkT[b][h>>2][k][h&3]  (4 consecutive h's for one k are 16 B contiguous;
//   adjacent k's are adjacent 16 B units -> lane stride 16 B = perfect
//   dwordx4 coalescing, 1 KB/instruction).

// ---------------------------------------------------------------------------
// Kernel 1: projections + exp2 epilogue. blockIdx.y: 0=q-side, 1=k-side.
// One block = RPB rows, 128 threads over h. M reads coalesced; X reads
// wave-uniform -> scalar loads. k-side writes the interleaved EkT layout
// (scattered dword stores — negligible, write-combined in L2).
// ---------------------------------------------------------------------------
__global__ __launch_bounds__(128) void proj_kernel(
    const float* __restrict__ queries, const float* __restrict__ keys,
    const float* __restrict__ U, const float* __restrict__ T,
    const float* __restrict__ bvec, const float* __restrict__ w,
    const float* __restrict__ wb,
    float* __restrict__ Eq, float* __restrict__ EkT, float* __restrict__ base)
{
    const int side = blockIdx.y;  // 0 = q-side, 1 = k-side
    const float* __restrict__ X = side ? keys : queries;
    const float* __restrict__ M = side ? T : U;

    const int t  = threadIdx.x;          // h index, 0..127
    const int r0 = blockIdx.x * RPB;     // first row of this block (global)

    // one thread computes base = w_bias + sum(w); overlapped with the GEMM
    if (side == 1 && blockIdx.x == 0 && t == 0) {
        float s = wb[0];
        for (int h = 0; h < H_; ++h) s += w[h];
        base[0] = s;
    }

    float acc[RPB];
#pragma unroll
    for (int i = 0; i < RPB; ++i) acc[i] = 0.f;

#pragma unroll 8
    for (int d = 0; d < H_; ++d) {
        float m = M[d * H_ + t];                      // coalesced across lanes
#pragma unroll
        for (int i = 0; i < RPB; ++i)                 // uniform addr -> s_load
            acc[i] = fmaf(X[(size_t)(r0 + i) * H_ + d], m, acc[i]);
    }

    const float C = 2.8853900817779268f;  // 2 * log2(e)
    if (side) {
        const int b     = r0 / LK_;       // RPB divides LK_, so one b/block
        const int kbase = r0 % LK_;
        const float bb  = bvec[t];
        float* __restrict__ y = EkT + (size_t)b * H_ * LK_
                              + (size_t)(t >> 2) * (LK_ * 4) + (t & 3);
#pragma unroll
        for (int i = 0; i < RPB; ++i)
            y[(size_t)(kbase + i) * 4] =
                __builtin_amdgcn_exp2f(C * (acc[i] + bb));
    } else {
#pragma unroll
        for (int i = 0; i < RPB; ++i)
            Eq[(size_t)(r0 + i) * H_ + t] =
                __builtin_amdgcn_exp2f(C * acc[i]);
    }
}

// ---------------------------------------------------------------------------
// Kernel 2: rational-pair reduction, 1 v_rcp_f32 per 4 h:
//   sum_i w_i/x_i over 4 terms = (n01*d23 + n23*d01) / (d01*d23),
//   x_i = fma(Eq_i, Ek_i, 1).  13 plain VALU + 1 trans per 4 elements.
// Thread owns one k; ek4 chunk (4 h, one coalesced dwordx4 from EkT) is
// reused across QPT=8 q-rows. Eq/w reads wave-uniform -> s_load.
// ---------------------------------------------------------------------------
__global__ __launch_bounds__(KTH) void score_kernel(
    const float* __restrict__ Eq, const float* __restrict__ EkT,
    const float* __restrict__ w, const float* __restrict__ base_p,
    float* __restrict__ out)
{
    const int b  = blockIdx.z;
    const int q0 = blockIdx.y * QPT;
    const int k  = blockIdx.x * KTH + threadIdx.x;

    const float* __restrict__ eqr = Eq + ((size_t)b * LQ_ + q0) * H_;
    const float* __restrict__ ekT = EkT + (size_t)b * H_ * LK_ + (size_t)k * 4;

    float acc[QPT];
#pragma unroll
    for (int i = 0; i < QPT; ++i) acc[i] = 0.f;

#pragma unroll 2
    for (int c = 0; c < H_; c += 4) {
        // lane stride 16 B -> one fully-coalesced global_load_dwordx4
        float4 ek4 = *(const float4*)(ekT + (size_t)(c >> 2) * (LK_ * 4));
        float w0 = w[c], w1 = w[c + 1], w2 = w[c + 2], w3 = w[c + 3];
#pragma unroll
        for (int q = 0; q < QPT; ++q) {
            const float* eq = eqr + q * H_ + c;          // uniform -> s_load
            float x0 = fmaf(eq[0], ek4.x, 1.f);
            float x1 = fmaf(eq[1], ek4.y, 1.f);
            float x2 = fmaf(eq[2], ek4.z, 1.f);
            float x3 = fmaf(eq[3], ek4.w, 1.f);
            float d01 = x0 * x1;
            float d23 = x2 * x3;
            float n01 = fmaf(w1, x0, w0 * x1);
            float n23 = fmaf(w3, x2, w2 * x3);
            float num = fmaf(n23, d01, n01 * d23);
            float den = d01 * d23;
            acc[q] = fmaf(num, __builtin_amdgcn_rcpf(den), acc[q]);
        }
    }

    const float base = base_p[0];                        // uniform -> s_load
#pragma unroll
    for (int q = 0; q < QPT; ++q)
        out[((size_t)b * LQ_ + q0 + q) * LK_ + k] = fmaf(-2.f, acc[q], base);
}

// ---------------------------------------------------------------------------
extern "C" void kernel_launch(void* const* d_in, const int* in_sizes, int n_in,
                              void* d_out, int out_size, void* d_ws, size_t ws_size,
                              hipStream_t stream)
{
    const float* queries = (const float*)d_in[0];
    const float* keys    = (const float*)d_in[1];
    const float* U       = (const float*)d_in[2];
    const float* T       = (const float*)d_in[3];
    const float* bvec    = (const float*)d_in[4];
    const float* w       = (const float*)d_in[5];
    const float* wb      = (const float*)d_in[6];
    float* out = (float*)d_out;

    float* Eq   = (float*)d_ws;                        // B*LQ*H fp32 = 1 MB
    float* EkT  = Eq + (size_t)B_ * LQ_ * H_;          // B*LK*H fp32 = 1 MB
    float* base = EkT + (size_t)B_ * LK_ * H_;         // 1 float

    proj_kernel<<<dim3((B_ * LQ_) / RPB, 2), 128, 0, stream>>>(
        queries, keys, U, T, bvec, w, wb, Eq, EkT, base);

    score_kernel<<<dim3(LK_ / KTH, LQ_ / QPT, B_), KTH, 0, stream>>>(
        Eq, EkT, w, base, out);
}